// Round 4
// baseline (813.627 us; speedup 1.0000x reference)
//
#include <hip/hip_runtime.h>
#include <hip/hip_bf16.h>

// Qwen3 MoE sparse block, MI355X/gfx950.
// Shapes: T=4096 tokens (B2 x S2048), H=2048, I=768, E=16, top-k=8.
// Round 4: break the register wall. gateup per-wave tile 64x32 per matrix
// (acc 128->64 regs), LDS 32KB dbuf, __launch_bounds__(256,3) -> 3 blocks/CU
// (12 waves/CU, m97 occupancy regime). Same for down_k. Fragment/swizzle
// math unchanged (verified since round 1).

typedef __attribute__((ext_vector_type(8))) short short8;   // 8 x bf16 (4 VGPRs) MFMA operand
typedef __attribute__((ext_vector_type(4))) float f32x4;    // MFMA accumulator

#define NUM_T 4096
#define DH    2048
#define DI    768
#define NE    16
#define DKD   (NE*DI)        // 12288
#define MAXMT 20             // m-tiles per expert (capacity 2560 tokens)
#define FINAL_ELEMS ((size_t)NUM_T*DH)

// ---- helpers -------------------------------------------------------------

static __device__ __forceinline__ unsigned short f2bf(float f) {
  unsigned int u = __builtin_bit_cast(unsigned int, f);
  u += 0x7fffu + ((u >> 16) & 1u);
  return (unsigned short)(u >> 16);
}

static __device__ __forceinline__ float bf2f(unsigned short b) {
  unsigned int u = ((unsigned int)b) << 16;
  return __builtin_bit_cast(float, u);
}

static __device__ __forceinline__ void gload16(const void* g, void* l) {
  __builtin_amdgcn_global_load_lds(
      (__attribute__((address_space(1))) void*)(g),
      (__attribute__((address_space(3))) void*)(l), 16, 0, 0);
}

// ---- kernel 1: hidden fp32 -> bf16 --------------------------------------

__global__ __launch_bounds__(256)
void cvt_hidden_k(const float* __restrict__ in, unsigned short* __restrict__ out) {
  size_t i = (size_t)blockIdx.x * 256 + threadIdx.x;
  const float4* p = (const float4*)in + i * 2;
  float4 a = p[0], b = p[1];
  short8 v;
  v[0] = (short)f2bf(a.x); v[1] = (short)f2bf(a.y);
  v[2] = (short)f2bf(a.z); v[3] = (short)f2bf(a.w);
  v[4] = (short)f2bf(b.x); v[5] = (short)f2bf(b.y);
  v[6] = (short)f2bf(b.z); v[7] = (short)f2bf(b.w);
  *(short8*)(out + i * 8) = v;
}

// ---- kernel 2: transpose + convert (per-expert matrices) ----------------

__global__ __launch_bounds__(256)
void transpose_cvt_k(const float* __restrict__ in, unsigned short* __restrict__ out,
                     int R, int C, long inStrideE, long outStrideE, int outLD) {
  __shared__ float tile[32][33];
  const float* inE = in + (size_t)blockIdx.z * inStrideE;
  unsigned short* outE = out + (size_t)blockIdx.z * outStrideE;
  int c0 = blockIdx.x * 32, r0 = blockIdx.y * 32;
  int tx = threadIdx.x, ty = threadIdx.y;
#pragma unroll
  for (int i = 0; i < 4; i++)
    tile[ty * 4 + i][tx] = inE[(size_t)(r0 + ty * 4 + i) * C + c0 + tx];
  __syncthreads();
#pragma unroll
  for (int i = 0; i < 4; i++) {
    int c = ty * 4 + i;
    outE[(size_t)(c0 + c) * outLD + r0 + tx] = f2bf(tile[tx][c]);
  }
}

// ---- kernel 3: router + softmax + top-8 + renorm -------------------------

__global__ __launch_bounds__(256)
void router_k(const float* __restrict__ x, const float* __restrict__ wr,
              float* __restrict__ logits_out, unsigned short* __restrict__ dwb) {
  int t = blockIdx.x;
  int tid = threadIdx.x, lane = tid & 63, wid = tid >> 6;
  float acc[16];
#pragma unroll
  for (int e = 0; e < 16; e++) acc[e] = 0.f;
  const float* xt = x + (size_t)t * DH;
  for (int i = tid; i < DH; i += 256) {
    float hv = xt[i];
    const float4* w4 = (const float4*)(wr + (size_t)i * 16);
#pragma unroll
    for (int q = 0; q < 4; q++) {
      float4 w = w4[q];
      acc[q * 4 + 0] += hv * w.x; acc[q * 4 + 1] += hv * w.y;
      acc[q * 4 + 2] += hv * w.z; acc[q * 4 + 3] += hv * w.w;
    }
  }
#pragma unroll
  for (int e = 0; e < 16; e++) {
#pragma unroll
    for (int off = 32; off; off >>= 1) acc[e] += __shfl_xor(acc[e], off, 64);
  }
  __shared__ float red[4][16];
  if (lane == 0) {
#pragma unroll
    for (int e = 0; e < 16; e++) red[wid][e] = acc[e];
  }
  __syncthreads();
  if (tid == 0) {
    float lg[16];
#pragma unroll
    for (int e = 0; e < 16; e++) lg[e] = red[0][e] + red[1][e] + red[2][e] + red[3][e];
    float mx = lg[0];
#pragma unroll
    for (int e = 1; e < 16; e++) mx = fmaxf(mx, lg[e]);
    float p[16], s = 0.f;
#pragma unroll
    for (int e = 0; e < 16; e++) { p[e] = __expf(lg[e] - mx); s += p[e]; }
    float inv = 1.f / s;
#pragma unroll
    for (int e = 0; e < 16; e++) p[e] *= inv;
    float tmp[16];
#pragma unroll
    for (int e = 0; e < 16; e++) tmp[e] = p[e];
    int idx[8]; float val[8]; float ts = 0.f;
#pragma unroll
    for (int k = 0; k < 8; k++) {
      int b = 0; float bv = tmp[0];
#pragma unroll
      for (int e = 1; e < 16; e++) { if (tmp[e] > bv) { bv = tmp[e]; b = e; } }
      idx[k] = b; val[k] = bv; tmp[b] = -1.f; ts += bv;
    }
    float dw[16];
#pragma unroll
    for (int e = 0; e < 16; e++) dw[e] = 0.f;
    float invt = 1.f / ts;
#pragma unroll
    for (int k = 0; k < 8; k++) dw[idx[k]] += val[k] * invt;
#pragma unroll
    for (int e = 0; e < 16; e++) {
      dwb[(size_t)t * 16 + e] = f2bf(dw[e]);
      logits_out[(size_t)t * 16 + e] = lg[e];
    }
  }
}

// ---- kernel 3b: per-expert compacted token lists (deterministic) --------

__global__ __launch_bounds__(256)
void build_lists_k(const unsigned short* __restrict__ dwb,
                   unsigned short* __restrict__ lst) {
  int e = blockIdx.x;
  int tid = threadIdx.x;
  unsigned short loc[16]; int c = 0;
#pragma unroll
  for (int j = 0; j < 16; j++) {
    int t = tid * 16 + j;
    if (dwb[(size_t)t * 16 + e] != 0) loc[c++] = (unsigned short)t;
  }
  __shared__ int sc[256];
  __shared__ int pre[257];
  sc[tid] = c;
  __syncthreads();
  if (tid == 0) {
    int s = 0;
    for (int i = 0; i < 256; i++) { pre[i] = s; s += sc[i]; }
    pre[256] = s;
  }
  __syncthreads();
  unsigned short* L = lst + (size_t)e * NUM_T;
  int base = pre[tid];
  for (int j = 0; j < c; j++) L[base + j] = loc[j];
  int total = pre[256];
  for (int i = total + tid; i < NUM_T; i += 256) L[i] = 0xFFFFu;
}

// ---- kernel 3c: zero-fill h_scaled --------------------------------------

__global__ __launch_bounds__(256)
void zfill_k(short8* __restrict__ p) {
  size_t i = (size_t)blockIdx.x * 256 + threadIdx.x;
  short8 z = {0,0,0,0,0,0,0,0};
  p[i] = z;
}

// ---- kernel 4: compacted per-expert gate/up GEMM + silu*up*w -> h_scaled
// Block tile: 128 tokens x 64 I-cols, 4 waves (2m x 2n), per-wave 64x32 per
// matrix (accg[4][2]+accu[4][2] = 64 regs). LDS 32KB dbuf. 3 blocks/CU.
// Grid flat 3840 = 8 XCD chunks x 480; logical e-major -> n-group -> mtile.

__global__ __launch_bounds__(256, 3)
void gateup_k(const unsigned short* __restrict__ hbf,
              const unsigned short* __restrict__ wgbt,
              const unsigned short* __restrict__ wubt,
              const unsigned short* __restrict__ dwb,
              const unsigned short* __restrict__ lst,
              unsigned short* __restrict__ hs) {
  // XCD-bijective swizzle: 3840 = 8 * 480
  const int bxr = blockIdx.x;
  const int wl  = (bxr & 7) * 480 + (bxr >> 3);
  const int e   = wl / 240;                 // 240 = 12 n-groups * 20 m-tiles
  const int rem = wl - e * 240;
  const int n0  = (rem / MAXMT) * 64;
  const int m0  = (rem % MAXMT) * 128;

  const unsigned short* L = lst + (size_t)e * NUM_T;
  if (L[m0] == 0xFFFFu) return;             // tile beyond count[e]

  const int tid = threadIdx.x, lane = tid & 63, wid = tid >> 6;
  const int wm = wid >> 1, wn = wid & 1;
  const int lr = lane & 15, lgp = lane >> 4;

  __shared__ alignas(16) unsigned short As [2 * 128 * 32];  // 16KB
  __shared__ alignas(16) unsigned short Bgs[2 *  64 * 32];  //  8KB
  __shared__ alignas(16) unsigned short Bus[2 *  64 * 32];  //  8KB

  f32x4 zero = {0.f, 0.f, 0.f, 0.f};
  f32x4 accg[4][2], accu[4][2];
#pragma unroll
  for (int m = 0; m < 4; m++)
#pragma unroll
    for (int n = 0; n < 2; n++) { accg[m][n] = zero; accu[m][n] = zero; }

  const unsigned short* wgE = wgbt + (size_t)e * DI * DH;
  const unsigned short* wuE = wubt + (size_t)e * DI * DH;

  const int srow    = lane >> 2;                                   // 0..15
  const int schunk8 = (((lane & 3) - ((lane >> 3) & 3)) & 3) * 8;  // inverse swizzle on src

  // gathered A rows (two 16-row halves per wave)
  const int ar0 = m0 + wid * 32 + srow, ar1 = ar0 + 16;
  const unsigned short t0 = L[ar0], t1 = L[ar1];
  const size_t prow0 = (t0 == 0xFFFFu) ? 0 : (size_t)t0;
  const size_t prow1 = (t1 == 0xFFFFu) ? 0 : (size_t)t1;
  // B rows: 64-row tile, each wave stages 16 rows
  const size_t brow = (size_t)(n0 + wid * 16 + srow);

  const int slot8 = (((lane >> 4) + ((lane >> 1) & 3)) & 3) * 8;   // fragment read slot

  auto stage = [&](int b, int k0) {
    unsigned short* Ab = As  + b * 4096 + wid * 1024;   // (wid*32)*32
    unsigned short* Gb = Bgs + b * 2048 + wid * 512;    // (wid*16)*32
    unsigned short* Ub = Bus + b * 2048 + wid * 512;
    gload16(hbf + prow0 * DH + k0 + schunk8, Ab);
    gload16(hbf + prow1 * DH + k0 + schunk8, Ab + 512);
    gload16(wgE + brow  * DH + k0 + schunk8, Gb);
    gload16(wuE + brow  * DH + k0 + schunk8, Ub);
  };

  auto compute = [&](int b) {
    const unsigned short* Ab = As  + b * 4096;
    const unsigned short* Gb = Bgs + b * 2048;
    const unsigned short* Ub = Bus + b * 2048;
    short8 a[4], bg[2], bu[2];
#pragma unroll
    for (int m = 0; m < 4; m++)
      a[m] = *(const short8*)(Ab + (wm * 64 + m * 16 + lr) * 32 + slot8);
#pragma unroll
    for (int n = 0; n < 2; n++) {
      bg[n] = *(const short8*)(Gb + (wn * 32 + n * 16 + lr) * 32 + slot8);
      bu[n] = *(const short8*)(Ub + (wn * 32 + n * 16 + lr) * 32 + slot8);
    }
#pragma unroll
    for (int m = 0; m < 4; m++)
#pragma unroll
      for (int n = 0; n < 2; n++) {
        accg[m][n] = __builtin_amdgcn_mfma_f32_16x16x32_bf16(a[m], bg[n], accg[m][n], 0, 0, 0);
        accu[m][n] = __builtin_amdgcn_mfma_f32_16x16x32_bf16(a[m], bu[n], accu[m][n], 0, 0, 0);
      }
  };

  // double-buffered K loop (DH/32 = 64 tiles, even)
  stage(0, 0);
  __syncthreads();
  int k0 = 0;
#pragma unroll 1
  for (; k0 + 64 < DH; k0 += 64) {
    stage(1, k0 + 32); compute(0); __syncthreads();
    stage(0, k0 + 64); compute(1); __syncthreads();
  }
  stage(1, k0 + 32); compute(0); __syncthreads();
  compute(1);

  // epilogue: silu(g)*u * w[t][e] -> bf16 h_scaled[t][e*DI + i]
#pragma unroll
  for (int m = 0; m < 4; m++) {
#pragma unroll
    for (int r = 0; r < 4; r++) {
      int mrow = m0 + wm * 64 + m * 16 + 4 * lgp + r;
      unsigned short tp = L[mrow];
      if (tp == 0xFFFFu) continue;
      float w = bf2f(dwb[(size_t)tp * 16 + e]);
#pragma unroll
      for (int n = 0; n < 2; n++) {
        float g = accg[m][n][r], u = accu[m][n][r];
        float sig = 1.f / (1.f + __expf(-g));
        float val = g * sig * u * w;
        hs[(size_t)tp * DKD + e * DI + n0 + wn * 32 + n * 16 + lr] = f2bf(val);
      }
    }
  }
}

// ---- kernel 5: down GEMM (4096 x 2048 x 12288) -> final fp32 ------------
// Double-buffered; XCD swizzle (512 = 8 * 64), m fastest for B-panel sharing.

__global__ __launch_bounds__(256, 3)
void down_k(const unsigned short* __restrict__ hsb,
            const unsigned short* __restrict__ wdbt,
            float* __restrict__ outp) {
  const int bxr = blockIdx.x;
  const int w   = (bxr & 7) * 64 + (bxr >> 3);
  const int m0  = (w & 31) << 7;
  const int n0  = (w >> 5) << 7;

  const int tid = threadIdx.x, lane = tid & 63, wid = tid >> 6;
  const int wm = wid >> 1, wn = wid & 1;
  const int lr = lane & 15, lgp = lane >> 4;

  __shared__ alignas(16) unsigned short As[2 * 128 * 32];
  __shared__ alignas(16) unsigned short Bs[2 * 128 * 32];

  f32x4 zero = {0.f, 0.f, 0.f, 0.f};
  f32x4 acc[4][4];
#pragma unroll
  for (int m = 0; m < 4; m++)
#pragma unroll
    for (int n = 0; n < 4; n++) acc[m][n] = zero;

  const int srow    = lane >> 2;
  const int schunk8 = (((lane & 3) - ((lane >> 3) & 3)) & 3) * 8;
  const int sOff0   = wid * 1024;
  const int sOff1   = sOff0 + 512;
  const size_t arow0 = (size_t)(m0 + wid * 32 + srow), arow1 = arow0 + 16;
  const size_t brow0 = (size_t)(n0 + wid * 32 + srow), brow1 = brow0 + 16;
  const int slot8 = (((lane >> 4) + ((lane >> 1) & 3)) & 3) * 8;

  auto stage = [&](int b, int k0) {
    const int off = b << 12;
    gload16(hsb  + arow0 * DKD + k0 + schunk8, As + off + sOff0);
    gload16(hsb  + arow1 * DKD + k0 + schunk8, As + off + sOff1);
    gload16(wdbt + brow0 * DKD + k0 + schunk8, Bs + off + sOff0);
    gload16(wdbt + brow1 * DKD + k0 + schunk8, Bs + off + sOff1);
  };

  auto compute = [&](int bsel) {
    const unsigned short* Ab = As + (bsel << 12);
    const unsigned short* Bb = Bs + (bsel << 12);
    short8 a[4], b[4];
#pragma unroll
    for (int m = 0; m < 4; m++)
      a[m] = *(const short8*)(Ab + (size_t)(wm * 64 + m * 16 + lr) * 32 + slot8);
#pragma unroll
    for (int n = 0; n < 4; n++)
      b[n] = *(const short8*)(Bb + (size_t)(wn * 64 + n * 16 + lr) * 32 + slot8);
#pragma unroll
    for (int m = 0; m < 4; m++)
#pragma unroll
      for (int n = 0; n < 4; n++)
        acc[m][n] = __builtin_amdgcn_mfma_f32_16x16x32_bf16(a[m], b[n], acc[m][n], 0, 0, 0);
  };

  stage(0, 0);
  __syncthreads();
  int k0 = 0;
#pragma unroll 1
  for (; k0 + 64 < DKD; k0 += 64) {
    stage(1, k0 + 32); compute(0); __syncthreads();
    stage(0, k0 + 64); compute(1); __syncthreads();
  }
  stage(1, k0 + 32); compute(0); __syncthreads();
  compute(1);

#pragma unroll
  for (int m = 0; m < 4; m++)
#pragma unroll
    for (int r = 0; r < 4; r++) {
      int t = m0 + wm * 64 + m * 16 + 4 * lgp + r;
#pragma unroll
      for (int n = 0; n < 4; n++)
        outp[(size_t)t * DH + n0 + wn * 64 + n * 16 + lr] = acc[m][n][r];
    }
}

// ---- launch --------------------------------------------------------------

extern "C" void kernel_launch(void* const* d_in, const int* in_sizes, int n_in,
                              void* d_out, int out_size, void* d_ws, size_t ws_size,
                              hipStream_t stream) {
  const float* x  = (const float*)d_in[0];   // [2,2048,2048]
  const float* wr = (const float*)d_in[1];   // [2048,16]
  const float* wg = (const float*)d_in[2];   // [16,2048,768]
  const float* wu = (const float*)d_in[3];   // [16,2048,768]
  const float* wd = (const float*)d_in[4];   // [16,768,2048]

  float* outF = (float*)d_out;               // final [T][H]
  float* outL = outF + FINAL_ELEMS;          // router logits [T][E]

  // workspace layout (bytes), total 218,365,952:
  //   hbf   @ 0          : 16,777,216   bf16 hidden [T][H]
  //   wgbt  @ 16,777,216 : 50,331,648   bf16 gate B^T [E][I][H]  (reused as wdbt)
  //   wubt  @ 67,108,864 : 50,331,648   bf16 up   B^T [E][I][H]
  //   hs    @ 117,440,512: 100,663,296  bf16 h_scaled [T][E*I]
  //   dwb   @ 218,103,808: 131,072      bf16 dense combine weights [T][E]
  //   lst   @ 218,234,880: 131,072      u16 per-expert token lists [E][T]
  if (ws_size < 218365952ull) return;
  char* ws = (char*)d_ws;
  unsigned short* hbf  = (unsigned short*)(ws);
  unsigned short* wgbt = (unsigned short*)(ws + 16777216);
  unsigned short* wubt = (unsigned short*)(ws + 67108864);
  unsigned short* hs   = (unsigned short*)(ws + 117440512);
  unsigned short* dwb  = (unsigned short*)(ws + 218103808);
  unsigned short* lst  = (unsigned short*)(ws + 218234880);
  unsigned short* wdbt = wgbt;  // aliased: down-transpose runs after gateup_k

  cvt_hidden_k<<<4096, 256, 0, stream>>>(x, hbf);
  transpose_cvt_k<<<dim3(24, 64, 16), dim3(32, 8), 0, stream>>>(
      wg, wgbt, 2048, 768, (long)2048 * 768, (long)768 * 2048, 2048);
  transpose_cvt_k<<<dim3(24, 64, 16), dim3(32, 8), 0, stream>>>(
      wu, wubt, 2048, 768, (long)2048 * 768, (long)768 * 2048, 2048);
  router_k<<<4096, 256, 0, stream>>>(x, wr, outL, dwb);
  build_lists_k<<<16, 256, 0, stream>>>(dwb, lst);
  zfill_k<<<24576, 256, 0, stream>>>((short8*)hs);
  gateup_k<<<3840, 256, 0, stream>>>(hbf, wgbt, wubt, dwb, lst, hs);
  transpose_cvt_k<<<dim3(64, 24, 16), dim3(32, 8), 0, stream>>>(
      wd, wdbt, 768, 2048, (long)768 * 2048, 768L, 12288);
  down_k<<<512, 256, 0, stream>>>(hs, wdbt, outF);
}

// Round 5
// 728.974 us; speedup vs baseline: 1.1161x; 1.1161x over previous
//
#include <hip/hip_runtime.h>
#include <hip/hip_bf16.h>

// Qwen3 MoE sparse block, MI355X/gfx950.
// Shapes: T=4096 tokens (B2 x S2048), H=2048, I=768, E=16, top-k=8.
// Round 5: counted-vmcnt 3-stage pipeline (T3/T4) in gateup_k and down_k:
// raw s_barrier + asm s_waitcnt vmcnt(4) keeps prefetch loads in flight
// across barriers (the __syncthreads vmcnt(0) drain was costing one full
// load latency per k-step). Loads issued 2 iterations ahead of use.

typedef __attribute__((ext_vector_type(8))) short short8;   // 8 x bf16 (4 VGPRs) MFMA operand
typedef __attribute__((ext_vector_type(4))) float f32x4;    // MFMA accumulator

#define NUM_T 4096
#define DH    2048
#define DI    768
#define NE    16
#define DKD   (NE*DI)        // 12288
#define MAXMT 20             // m-tiles per expert (capacity 2560 tokens)
#define FINAL_ELEMS ((size_t)NUM_T*DH)

// ---- helpers -------------------------------------------------------------

static __device__ __forceinline__ unsigned short f2bf(float f) {
  unsigned int u = __builtin_bit_cast(unsigned int, f);
  u += 0x7fffu + ((u >> 16) & 1u);
  return (unsigned short)(u >> 16);
}

static __device__ __forceinline__ float bf2f(unsigned short b) {
  unsigned int u = ((unsigned int)b) << 16;
  return __builtin_bit_cast(float, u);
}

static __device__ __forceinline__ void gload16(const void* g, void* l) {
  __builtin_amdgcn_global_load_lds(
      (__attribute__((address_space(1))) void*)(g),
      (__attribute__((address_space(3))) void*)(l), 16, 0, 0);
}

// ---- kernel 1: hidden fp32 -> bf16 --------------------------------------

__global__ __launch_bounds__(256)
void cvt_hidden_k(const float* __restrict__ in, unsigned short* __restrict__ out) {
  size_t i = (size_t)blockIdx.x * 256 + threadIdx.x;
  const float4* p = (const float4*)in + i * 2;
  float4 a = p[0], b = p[1];
  short8 v;
  v[0] = (short)f2bf(a.x); v[1] = (short)f2bf(a.y);
  v[2] = (short)f2bf(a.z); v[3] = (short)f2bf(a.w);
  v[4] = (short)f2bf(b.x); v[5] = (short)f2bf(b.y);
  v[6] = (short)f2bf(b.z); v[7] = (short)f2bf(b.w);
  *(short8*)(out + i * 8) = v;
}

// ---- kernel 2: transpose + convert (per-expert matrices) ----------------

__global__ __launch_bounds__(256)
void transpose_cvt_k(const float* __restrict__ in, unsigned short* __restrict__ out,
                     int R, int C, long inStrideE, long outStrideE, int outLD) {
  __shared__ float tile[32][33];
  const float* inE = in + (size_t)blockIdx.z * inStrideE;
  unsigned short* outE = out + (size_t)blockIdx.z * outStrideE;
  int c0 = blockIdx.x * 32, r0 = blockIdx.y * 32;
  int tx = threadIdx.x, ty = threadIdx.y;
#pragma unroll
  for (int i = 0; i < 4; i++)
    tile[ty * 4 + i][tx] = inE[(size_t)(r0 + ty * 4 + i) * C + c0 + tx];
  __syncthreads();
#pragma unroll
  for (int i = 0; i < 4; i++) {
    int c = ty * 4 + i;
    outE[(size_t)(c0 + c) * outLD + r0 + tx] = f2bf(tile[tx][c]);
  }
}

// ---- kernel 3: router + softmax + top-8 + renorm -------------------------

__global__ __launch_bounds__(256)
void router_k(const float* __restrict__ x, const float* __restrict__ wr,
              float* __restrict__ logits_out, unsigned short* __restrict__ dwb) {
  int t = blockIdx.x;
  int tid = threadIdx.x, lane = tid & 63, wid = tid >> 6;
  float acc[16];
#pragma unroll
  for (int e = 0; e < 16; e++) acc[e] = 0.f;
  const float* xt = x + (size_t)t * DH;
  for (int i = tid; i < DH; i += 256) {
    float hv = xt[i];
    const float4* w4 = (const float4*)(wr + (size_t)i * 16);
#pragma unroll
    for (int q = 0; q < 4; q++) {
      float4 w = w4[q];
      acc[q * 4 + 0] += hv * w.x; acc[q * 4 + 1] += hv * w.y;
      acc[q * 4 + 2] += hv * w.z; acc[q * 4 + 3] += hv * w.w;
    }
  }
#pragma unroll
  for (int e = 0; e < 16; e++) {
#pragma unroll
    for (int off = 32; off; off >>= 1) acc[e] += __shfl_xor(acc[e], off, 64);
  }
  __shared__ float red[4][16];
  if (lane == 0) {
#pragma unroll
    for (int e = 0; e < 16; e++) red[wid][e] = acc[e];
  }
  __syncthreads();
  if (tid == 0) {
    float lg[16];
#pragma unroll
    for (int e = 0; e < 16; e++) lg[e] = red[0][e] + red[1][e] + red[2][e] + red[3][e];
    float mx = lg[0];
#pragma unroll
    for (int e = 1; e < 16; e++) mx = fmaxf(mx, lg[e]);
    float p[16], s = 0.f;
#pragma unroll
    for (int e = 0; e < 16; e++) { p[e] = __expf(lg[e] - mx); s += p[e]; }
    float inv = 1.f / s;
#pragma unroll
    for (int e = 0; e < 16; e++) p[e] *= inv;
    float tmp[16];
#pragma unroll
    for (int e = 0; e < 16; e++) tmp[e] = p[e];
    int idx[8]; float val[8]; float ts = 0.f;
#pragma unroll
    for (int k = 0; k < 8; k++) {
      int b = 0; float bv = tmp[0];
#pragma unroll
      for (int e = 1; e < 16; e++) { if (tmp[e] > bv) { bv = tmp[e]; b = e; } }
      idx[k] = b; val[k] = bv; tmp[b] = -1.f; ts += bv;
    }
    float dw[16];
#pragma unroll
    for (int e = 0; e < 16; e++) dw[e] = 0.f;
    float invt = 1.f / ts;
#pragma unroll
    for (int k = 0; k < 8; k++) dw[idx[k]] += val[k] * invt;
#pragma unroll
    for (int e = 0; e < 16; e++) {
      dwb[(size_t)t * 16 + e] = f2bf(dw[e]);
      logits_out[(size_t)t * 16 + e] = lg[e];
    }
  }
}

// ---- kernel 3b: per-expert compacted token lists (deterministic) --------

__global__ __launch_bounds__(256)
void build_lists_k(const unsigned short* __restrict__ dwb,
                   unsigned short* __restrict__ lst) {
  int e = blockIdx.x;
  int tid = threadIdx.x;
  unsigned short loc[16]; int c = 0;
#pragma unroll
  for (int j = 0; j < 16; j++) {
    int t = tid * 16 + j;
    if (dwb[(size_t)t * 16 + e] != 0) loc[c++] = (unsigned short)t;
  }
  __shared__ int sc[256];
  __shared__ int pre[257];
  sc[tid] = c;
  __syncthreads();
  if (tid == 0) {
    int s = 0;
    for (int i = 0; i < 256; i++) { pre[i] = s; s += sc[i]; }
    pre[256] = s;
  }
  __syncthreads();
  unsigned short* L = lst + (size_t)e * NUM_T;
  int base = pre[tid];
  for (int j = 0; j < c; j++) L[base + j] = loc[j];
  int total = pre[256];
  for (int i = total + tid; i < NUM_T; i += 256) L[i] = 0xFFFFu;
}

// ---- kernel 3c: zero-fill h_scaled --------------------------------------

__global__ __launch_bounds__(256)
void zfill_k(short8* __restrict__ p) {
  size_t i = (size_t)blockIdx.x * 256 + threadIdx.x;
  short8 z = {0,0,0,0,0,0,0,0};
  p[i] = z;
}

// ---- kernel 4: compacted per-expert gate/up GEMM + silu*up*w -> h_scaled
// Block tile: 128 tokens x 64 I-cols, 4 waves (2m x 2n), per-wave 64x32 per
// matrix. 3-stage LDS pipeline (48KB), counted vmcnt(4), 3 blocks/CU.
// Grid flat 3840 = 8 XCD chunks x 480; logical e-major -> n-group -> mtile.

__global__ __launch_bounds__(256, 3)
void gateup_k(const unsigned short* __restrict__ hbf,
              const unsigned short* __restrict__ wgbt,
              const unsigned short* __restrict__ wubt,
              const unsigned short* __restrict__ dwb,
              const unsigned short* __restrict__ lst,
              unsigned short* __restrict__ hs) {
  // XCD-bijective swizzle: 3840 = 8 * 480
  const int bxr = blockIdx.x;
  const int wl  = (bxr & 7) * 480 + (bxr >> 3);
  const int e   = wl / 240;                 // 240 = 12 n-groups * 20 m-tiles
  const int rem = wl - e * 240;
  const int n0  = (rem / MAXMT) * 64;
  const int m0  = (rem % MAXMT) * 128;

  const unsigned short* L = lst + (size_t)e * NUM_T;
  if (L[m0] == 0xFFFFu) return;             // tile beyond count[e]

  const int tid = threadIdx.x, lane = tid & 63, wid = tid >> 6;
  const int wm = wid >> 1, wn = wid & 1;
  const int lr = lane & 15, lgp = lane >> 4;

  __shared__ alignas(16) unsigned short As [3 * 128 * 32];  // 24KB
  __shared__ alignas(16) unsigned short Bgs[3 *  64 * 32];  // 12KB
  __shared__ alignas(16) unsigned short Bus[3 *  64 * 32];  // 12KB

  f32x4 zero = {0.f, 0.f, 0.f, 0.f};
  f32x4 accg[4][2], accu[4][2];
#pragma unroll
  for (int m = 0; m < 4; m++)
#pragma unroll
    for (int n = 0; n < 2; n++) { accg[m][n] = zero; accu[m][n] = zero; }

  const unsigned short* wgE = wgbt + (size_t)e * DI * DH;
  const unsigned short* wuE = wubt + (size_t)e * DI * DH;

  const int srow    = lane >> 2;                                   // 0..15
  const int schunk8 = (((lane & 3) - ((lane >> 3) & 3)) & 3) * 8;  // inverse swizzle on src

  const int ar0 = m0 + wid * 32 + srow, ar1 = ar0 + 16;
  const unsigned short t0 = L[ar0], t1 = L[ar1];
  const size_t prow0 = (t0 == 0xFFFFu) ? 0 : (size_t)t0;
  const size_t prow1 = (t1 == 0xFFFFu) ? 0 : (size_t)t1;
  const size_t brow = (size_t)(n0 + wid * 16 + srow);

  const int slot8 = (((lane >> 4) + ((lane >> 1) & 3)) & 3) * 8;   // fragment read slot

  auto stage = [&](int b, int k0) {           // 4 loads per wave
    unsigned short* Ab = As  + b * 4096 + wid * 1024;
    unsigned short* Gb = Bgs + b * 2048 + wid * 512;
    unsigned short* Ub = Bus + b * 2048 + wid * 512;
    gload16(hbf + prow0 * DH + k0 + schunk8, Ab);
    gload16(hbf + prow1 * DH + k0 + schunk8, Ab + 512);
    gload16(wgE + brow  * DH + k0 + schunk8, Gb);
    gload16(wuE + brow  * DH + k0 + schunk8, Ub);
  };

  auto compute = [&](int b) {
    const unsigned short* Ab = As  + b * 4096;
    const unsigned short* Gb = Bgs + b * 2048;
    const unsigned short* Ub = Bus + b * 2048;
    short8 a[4], bg[2], bu[2];
#pragma unroll
    for (int m = 0; m < 4; m++)
      a[m] = *(const short8*)(Ab + (wm * 64 + m * 16 + lr) * 32 + slot8);
#pragma unroll
    for (int n = 0; n < 2; n++) {
      bg[n] = *(const short8*)(Gb + (wn * 32 + n * 16 + lr) * 32 + slot8);
      bu[n] = *(const short8*)(Ub + (wn * 32 + n * 16 + lr) * 32 + slot8);
    }
#pragma unroll
    for (int m = 0; m < 4; m++)
#pragma unroll
      for (int n = 0; n < 2; n++) {
        accg[m][n] = __builtin_amdgcn_mfma_f32_16x16x32_bf16(a[m], bg[n], accg[m][n], 0, 0, 0);
        accu[m][n] = __builtin_amdgcn_mfma_f32_16x16x32_bf16(a[m], bu[n], accu[m][n], 0, 0, 0);
      }
  };

  // 3-stage pipeline over NT = 64 k-tiles; loads for tile i issued at i-2.
  const int NT = DH / 32;
  stage(0, 0);
  stage(1, 32);
  int bc = 0, bs = 2;
#pragma unroll 1
  for (int i = 0; i < NT - 1; ++i) {
    asm volatile("s_waitcnt vmcnt(4)" ::: "memory");   // oldest stage complete
    __builtin_amdgcn_s_barrier();
    __builtin_amdgcn_sched_barrier(0);
    compute(bc);
    if (i + 2 < NT) stage(bs, (i + 2) * 32);
    bc = (bc == 2) ? 0 : bc + 1;
    bs = (bs == 2) ? 0 : bs + 1;
  }
  asm volatile("s_waitcnt vmcnt(0)" ::: "memory");
  __builtin_amdgcn_s_barrier();
  __builtin_amdgcn_sched_barrier(0);
  compute(bc);

  // epilogue: silu(g)*u * w[t][e] -> bf16 h_scaled[t][e*DI + i]
#pragma unroll
  for (int m = 0; m < 4; m++) {
#pragma unroll
    for (int r = 0; r < 4; r++) {
      int mrow = m0 + wm * 64 + m * 16 + 4 * lgp + r;
      unsigned short tp = L[mrow];
      if (tp == 0xFFFFu) continue;
      float w = bf2f(dwb[(size_t)tp * 16 + e]);
#pragma unroll
      for (int n = 0; n < 2; n++) {
        float g = accg[m][n][r], u = accu[m][n][r];
        float sig = 1.f / (1.f + __expf(-g));
        float val = g * sig * u * w;
        hs[(size_t)tp * DKD + e * DI + n0 + wn * 32 + n * 16 + lr] = f2bf(val);
      }
    }
  }
}

// ---- kernel 5: down GEMM (4096 x 2048 x 12288) -> final fp32 ------------
// 3-stage counted-vmcnt pipeline; XCD swizzle (512 = 8 * 64), m fastest.

__global__ __launch_bounds__(256, 3)
void down_k(const unsigned short* __restrict__ hsb,
            const unsigned short* __restrict__ wdbt,
            float* __restrict__ outp) {
  const int bxr = blockIdx.x;
  const int w   = (bxr & 7) * 64 + (bxr >> 3);
  const int m0  = (w & 31) << 7;
  const int n0  = (w >> 5) << 7;

  const int tid = threadIdx.x, lane = tid & 63, wid = tid >> 6;
  const int wm = wid >> 1, wn = wid & 1;
  const int lr = lane & 15, lgp = lane >> 4;

  __shared__ alignas(16) unsigned short As[3 * 128 * 32];  // 24KB
  __shared__ alignas(16) unsigned short Bs[3 * 128 * 32];  // 24KB

  f32x4 zero = {0.f, 0.f, 0.f, 0.f};
  f32x4 acc[4][4];
#pragma unroll
  for (int m = 0; m < 4; m++)
#pragma unroll
    for (int n = 0; n < 4; n++) acc[m][n] = zero;

  const int srow    = lane >> 2;
  const int schunk8 = (((lane & 3) - ((lane >> 3) & 3)) & 3) * 8;
  const int sOff0   = wid * 1024;
  const int sOff1   = sOff0 + 512;
  const size_t arow0 = (size_t)(m0 + wid * 32 + srow), arow1 = arow0 + 16;
  const size_t brow0 = (size_t)(n0 + wid * 32 + srow), brow1 = brow0 + 16;
  const int slot8 = (((lane >> 4) + ((lane >> 1) & 3)) & 3) * 8;

  auto stage = [&](int b, int k0) {           // 4 loads per wave
    unsigned short* Ab = As + b * 4096;
    unsigned short* Bb = Bs + b * 4096;
    gload16(hsb  + arow0 * DKD + k0 + schunk8, Ab + sOff0);
    gload16(hsb  + arow1 * DKD + k0 + schunk8, Ab + sOff1);
    gload16(wdbt + brow0 * DKD + k0 + schunk8, Bb + sOff0);
    gload16(wdbt + brow1 * DKD + k0 + schunk8, Bb + sOff1);
  };

  auto compute = [&](int bsel) {
    const unsigned short* Ab = As + bsel * 4096;
    const unsigned short* Bb = Bs + bsel * 4096;
    short8 a[4], b[4];
#pragma unroll
    for (int m = 0; m < 4; m++)
      a[m] = *(const short8*)(Ab + (size_t)(wm * 64 + m * 16 + lr) * 32 + slot8);
#pragma unroll
    for (int n = 0; n < 4; n++)
      b[n] = *(const short8*)(Bb + (size_t)(wn * 64 + n * 16 + lr) * 32 + slot8);
#pragma unroll
    for (int m = 0; m < 4; m++)
#pragma unroll
      for (int n = 0; n < 4; n++)
        acc[m][n] = __builtin_amdgcn_mfma_f32_16x16x32_bf16(a[m], b[n], acc[m][n], 0, 0, 0);
  };

  const int NT = DKD / 32;                   // 384
  stage(0, 0);
  stage(1, 32);
  int bc = 0, bs = 2;
#pragma unroll 1
  for (int i = 0; i < NT - 1; ++i) {
    asm volatile("s_waitcnt vmcnt(4)" ::: "memory");
    __builtin_amdgcn_s_barrier();
    __builtin_amdgcn_sched_barrier(0);
    compute(bc);
    if (i + 2 < NT) stage(bs, (i + 2) * 32);
    bc = (bc == 2) ? 0 : bc + 1;
    bs = (bs == 2) ? 0 : bs + 1;
  }
  asm volatile("s_waitcnt vmcnt(0)" ::: "memory");
  __builtin_amdgcn_s_barrier();
  __builtin_amdgcn_sched_barrier(0);
  compute(bc);

#pragma unroll
  for (int m = 0; m < 4; m++)
#pragma unroll
    for (int r = 0; r < 4; r++) {
      int t = m0 + wm * 64 + m * 16 + 4 * lgp + r;
#pragma unroll
      for (int n = 0; n < 4; n++)
        outp[(size_t)t * DH + n0 + wn * 64 + n * 16 + lr] = acc[m][n][r];
    }
}

// ---- launch --------------------------------------------------------------

extern "C" void kernel_launch(void* const* d_in, const int* in_sizes, int n_in,
                              void* d_out, int out_size, void* d_ws, size_t ws_size,
                              hipStream_t stream) {
  const float* x  = (const float*)d_in[0];   // [2,2048,2048]
  const float* wr = (const float*)d_in[1];   // [2048,16]
  const float* wg = (const float*)d_in[2];   // [16,2048,768]
  const float* wu = (const float*)d_in[3];   // [16,2048,768]
  const float* wd = (const float*)d_in[4];   // [16,768,2048]

  float* outF = (float*)d_out;               // final [T][H]
  float* outL = outF + FINAL_ELEMS;          // router logits [T][E]

  // workspace layout (bytes), total 218,365,952:
  //   hbf   @ 0          : 16,777,216   bf16 hidden [T][H]
  //   wgbt  @ 16,777,216 : 50,331,648   bf16 gate B^T [E][I][H]  (reused as wdbt)
  //   wubt  @ 67,108,864 : 50,331,648   bf16 up   B^T [E][I][H]
  //   hs    @ 117,440,512: 100,663,296  bf16 h_scaled [T][E*I]
  //   dwb   @ 218,103,808: 131,072      bf16 dense combine weights [T][E]
  //   lst   @ 218,234,880: 131,072      u16 per-expert token lists [E][T]
  if (ws_size < 218365952ull) return;
  char* ws = (char*)d_ws;
  unsigned short* hbf  = (unsigned short*)(ws);
  unsigned short* wgbt = (unsigned short*)(ws + 16777216);
  unsigned short* wubt = (unsigned short*)(ws + 67108864);
  unsigned short* hs   = (unsigned short*)(ws + 117440512);
  unsigned short* dwb  = (unsigned short*)(ws + 218103808);
  unsigned short* lst  = (unsigned short*)(ws + 218234880);
  unsigned short* wdbt = wgbt;  // aliased: down-transpose runs after gateup_k

  cvt_hidden_k<<<4096, 256, 0, stream>>>(x, hbf);
  transpose_cvt_k<<<dim3(24, 64, 16), dim3(32, 8), 0, stream>>>(
      wg, wgbt, 2048, 768, (long)2048 * 768, (long)768 * 2048, 2048);
  transpose_cvt_k<<<dim3(24, 64, 16), dim3(32, 8), 0, stream>>>(
      wu, wubt, 2048, 768, (long)2048 * 768, (long)768 * 2048, 2048);
  router_k<<<4096, 256, 0, stream>>>(x, wr, outL, dwb);
  build_lists_k<<<16, 256, 0, stream>>>(dwb, lst);
  zfill_k<<<24576, 256, 0, stream>>>((short8*)hs);
  gateup_k<<<3840, 256, 0, stream>>>(hbf, wgbt, wubt, dwb, lst, hs);
  transpose_cvt_k<<<dim3(64, 24, 16), dim3(32, 8), 0, stream>>>(
      wd, wdbt, 768, 2048, (long)768 * 2048, 768L, 12288);
  down_k<<<512, 256, 0, stream>>>(hs, wdbt, outF);
}

// Round 6
// 638.792 us; speedup vs baseline: 1.2737x; 1.1412x over previous
//
#include <hip/hip_runtime.h>
#include <hip/hip_bf16.h>

// Qwen3 MoE sparse block, MI355X/gfx950.
// Shapes: T=4096 tokens (B2 x S2048), H=2048, I=768, E=16, top-k=8.
// Round 6: sparse down projection. Per-expert down GEMM over compacted rows
// (103 GF instead of dense 206 GF), scattered into an 8-slot buffer
// slot[s][t][h] (each (t,s) written exactly once), then reduced. Tokens
// processed in two halves so the slot buffer (67.1MB) aliases hbf+wubt.
// zfill eliminated. Gate/up GEMM keeps the r5 counted-vmcnt pipeline.

typedef __attribute__((ext_vector_type(8))) short short8;   // 8 x bf16 (4 VGPRs) MFMA operand
typedef __attribute__((ext_vector_type(4))) float f32x4;    // MFMA accumulator

#define NUM_T 4096
#define DH    2048
#define DI    768
#define NE    16
#define DKD   (NE*DI)        // 12288 (dense wdbt row length)
#define MAXMT 20             // gateup m-tiles per expert (capacity 2560 tokens)
#define HSC_CAP 2560         // compacted rows capacity per expert
#define TOK_HALF 2048
#define FINAL_ELEMS ((size_t)NUM_T*DH)

// ---- helpers -------------------------------------------------------------

static __device__ __forceinline__ unsigned short f2bf(float f) {
  unsigned int u = __builtin_bit_cast(unsigned int, f);
  u += 0x7fffu + ((u >> 16) & 1u);
  return (unsigned short)(u >> 16);
}

static __device__ __forceinline__ float bf2f(unsigned short b) {
  unsigned int u = ((unsigned int)b) << 16;
  return __builtin_bit_cast(float, u);
}

static __device__ __forceinline__ void gload16(const void* g, void* l) {
  __builtin_amdgcn_global_load_lds(
      (__attribute__((address_space(1))) void*)(g),
      (__attribute__((address_space(3))) void*)(l), 16, 0, 0);
}

// ---- kernel 1: hidden fp32 -> bf16 --------------------------------------

__global__ __launch_bounds__(256)
void cvt_hidden_k(const float* __restrict__ in, unsigned short* __restrict__ out) {
  size_t i = (size_t)blockIdx.x * 256 + threadIdx.x;
  const float4* p = (const float4*)in + i * 2;
  float4 a = p[0], b = p[1];
  short8 v;
  v[0] = (short)f2bf(a.x); v[1] = (short)f2bf(a.y);
  v[2] = (short)f2bf(a.z); v[3] = (short)f2bf(a.w);
  v[4] = (short)f2bf(b.x); v[5] = (short)f2bf(b.y);
  v[6] = (short)f2bf(b.z); v[7] = (short)f2bf(b.w);
  *(short8*)(out + i * 8) = v;
}

// ---- kernel 2: transpose + convert (per-expert matrices) ----------------

__global__ __launch_bounds__(256)
void transpose_cvt_k(const float* __restrict__ in, unsigned short* __restrict__ out,
                     int R, int C, long inStrideE, long outStrideE, int outLD) {
  __shared__ float tile[32][33];
  const float* inE = in + (size_t)blockIdx.z * inStrideE;
  unsigned short* outE = out + (size_t)blockIdx.z * outStrideE;
  int c0 = blockIdx.x * 32, r0 = blockIdx.y * 32;
  int tx = threadIdx.x, ty = threadIdx.y;
#pragma unroll
  for (int i = 0; i < 4; i++)
    tile[ty * 4 + i][tx] = inE[(size_t)(r0 + ty * 4 + i) * C + c0 + tx];
  __syncthreads();
#pragma unroll
  for (int i = 0; i < 4; i++) {
    int c = ty * 4 + i;
    outE[(size_t)(c0 + c) * outLD + r0 + tx] = f2bf(tile[tx][c]);
  }
}

// ---- kernel 3: router + softmax + top-8 + renorm + slot assignment ------

__global__ __launch_bounds__(256)
void router_k(const float* __restrict__ x, const float* __restrict__ wr,
              float* __restrict__ logits_out, unsigned short* __restrict__ dwb,
              unsigned char* __restrict__ slt) {
  int t = blockIdx.x;
  int tid = threadIdx.x, lane = tid & 63, wid = tid >> 6;
  float acc[16];
#pragma unroll
  for (int e = 0; e < 16; e++) acc[e] = 0.f;
  const float* xt = x + (size_t)t * DH;
  for (int i = tid; i < DH; i += 256) {
    float hv = xt[i];
    const float4* w4 = (const float4*)(wr + (size_t)i * 16);
#pragma unroll
    for (int q = 0; q < 4; q++) {
      float4 w = w4[q];
      acc[q * 4 + 0] += hv * w.x; acc[q * 4 + 1] += hv * w.y;
      acc[q * 4 + 2] += hv * w.z; acc[q * 4 + 3] += hv * w.w;
    }
  }
#pragma unroll
  for (int e = 0; e < 16; e++) {
#pragma unroll
    for (int off = 32; off; off >>= 1) acc[e] += __shfl_xor(acc[e], off, 64);
  }
  __shared__ float red[4][16];
  if (lane == 0) {
#pragma unroll
    for (int e = 0; e < 16; e++) red[wid][e] = acc[e];
  }
  __syncthreads();
  if (tid == 0) {
    float lg[16];
#pragma unroll
    for (int e = 0; e < 16; e++) lg[e] = red[0][e] + red[1][e] + red[2][e] + red[3][e];
    float mx = lg[0];
#pragma unroll
    for (int e = 1; e < 16; e++) mx = fmaxf(mx, lg[e]);
    float p[16], s = 0.f;
#pragma unroll
    for (int e = 0; e < 16; e++) { p[e] = __expf(lg[e] - mx); s += p[e]; }
    float inv = 1.f / s;
#pragma unroll
    for (int e = 0; e < 16; e++) p[e] *= inv;
    float tmp[16];
#pragma unroll
    for (int e = 0; e < 16; e++) tmp[e] = p[e];
    int idx[8]; float val[8]; float ts = 0.f;
#pragma unroll
    for (int k = 0; k < 8; k++) {
      int b = 0; float bv = tmp[0];
#pragma unroll
      for (int e = 1; e < 16; e++) { if (tmp[e] > bv) { bv = tmp[e]; b = e; } }
      idx[k] = b; val[k] = bv; tmp[b] = -1.f; ts += bv;
    }
    float dw[16];
    unsigned char sl[16];
#pragma unroll
    for (int e = 0; e < 16; e++) { dw[e] = 0.f; sl[e] = 0xFF; }
    float invt = 1.f / ts;
#pragma unroll
    for (int k = 0; k < 8; k++) { dw[idx[k]] += val[k] * invt; sl[idx[k]] = (unsigned char)k; }
#pragma unroll
    for (int e = 0; e < 16; e++) {
      dwb[(size_t)t * 16 + e] = f2bf(dw[e]);
      slt[(size_t)t * 16 + e] = sl[e];
      logits_out[(size_t)t * 16 + e] = lg[e];
    }
  }
}

// ---- kernel 3b: per-expert compacted token lists + split metadata -------
// entry = t | (slot<<12), bit15 clear; 0xFFFF sentinel.
// meta[e*2] = count of half-0 tokens (t<2048), meta[e*2+1] = total count.

__global__ __launch_bounds__(256)
void build_lists_k(const unsigned short* __restrict__ dwb,
                   const unsigned char* __restrict__ slt,
                   unsigned short* __restrict__ lst, int* __restrict__ meta) {
  int e = blockIdx.x;
  int tid = threadIdx.x;
  unsigned short loc[16]; int c = 0;
#pragma unroll
  for (int j = 0; j < 16; j++) {
    int t = tid * 16 + j;
    if (dwb[(size_t)t * 16 + e] != 0) {
      unsigned short s = slt[(size_t)t * 16 + e];
      loc[c++] = (unsigned short)(t | (s << 12));
    }
  }
  __shared__ int sc[256];
  __shared__ int pre[257];
  sc[tid] = c;
  __syncthreads();
  if (tid == 0) {
    int s = 0;
    for (int i = 0; i < 256; i++) { pre[i] = s; s += sc[i]; }
    pre[256] = s;
  }
  __syncthreads();
  unsigned short* L = lst + (size_t)e * NUM_T;
  int base = pre[tid];
  for (int j = 0; j < c; j++) L[base + j] = loc[j];
  int total = pre[256];
  for (int i = total + tid; i < NUM_T; i += 256) L[i] = 0xFFFFu;
  if (tid == 0) { meta[e * 2] = pre[128]; meta[e * 2 + 1] = total; }
}

// ---- kernel 4: compacted per-expert gate/up GEMM + silu*up*w -> hsC -----
// Block tile: 128 tokens x 64 I-cols, 4 waves (2m x 2n). 3-stage counted-
// vmcnt pipeline (48KB LDS), 3 blocks/CU. Writes compacted hsC[e][row][i].

__global__ __launch_bounds__(256, 3)
void gateup_k(const unsigned short* __restrict__ hbf,
              const unsigned short* __restrict__ wgbt,
              const unsigned short* __restrict__ wubt,
              const unsigned short* __restrict__ dwb,
              const unsigned short* __restrict__ lst,
              unsigned short* __restrict__ hsC) {
  // XCD-bijective swizzle: 3840 = 8 * 480
  const int bxr = blockIdx.x;
  const int wl  = (bxr & 7) * 480 + (bxr >> 3);
  const int e   = wl / 240;                 // 240 = 12 n-groups * 20 m-tiles
  const int rem = wl - e * 240;
  const int n0  = (rem / MAXMT) * 64;
  const int m0  = (rem % MAXMT) * 128;

  const unsigned short* L = lst + (size_t)e * NUM_T;
  if (L[m0] & 0x8000) return;               // tile beyond count[e]

  const int tid = threadIdx.x, lane = tid & 63, wid = tid >> 6;
  const int wm = wid >> 1, wn = wid & 1;
  const int lr = lane & 15, lgp = lane >> 4;

  __shared__ alignas(16) unsigned short As [3 * 128 * 32];  // 24KB
  __shared__ alignas(16) unsigned short Bgs[3 *  64 * 32];  // 12KB
  __shared__ alignas(16) unsigned short Bus[3 *  64 * 32];  // 12KB

  f32x4 zero = {0.f, 0.f, 0.f, 0.f};
  f32x4 accg[4][2], accu[4][2];
#pragma unroll
  for (int m = 0; m < 4; m++)
#pragma unroll
    for (int n = 0; n < 2; n++) { accg[m][n] = zero; accu[m][n] = zero; }

  const unsigned short* wgE = wgbt + (size_t)e * DI * DH;
  const unsigned short* wuE = wubt + (size_t)e * DI * DH;

  const int srow    = lane >> 2;                                   // 0..15
  const int schunk8 = (((lane & 3) - ((lane >> 3) & 3)) & 3) * 8;  // inverse swizzle on src

  const int ar0 = m0 + wid * 32 + srow, ar1 = ar0 + 16;
  const unsigned short t0 = L[ar0], t1 = L[ar1];
  const size_t prow0 = (t0 & 0x8000) ? 0 : (size_t)(t0 & 0xFFF);
  const size_t prow1 = (t1 & 0x8000) ? 0 : (size_t)(t1 & 0xFFF);
  const size_t brow = (size_t)(n0 + wid * 16 + srow);

  const int slot8 = (((lane >> 4) + ((lane >> 1) & 3)) & 3) * 8;   // fragment read slot

  auto stage = [&](int b, int k0) {           // 4 loads per wave
    unsigned short* Ab = As  + b * 4096 + wid * 1024;
    unsigned short* Gb = Bgs + b * 2048 + wid * 512;
    unsigned short* Ub = Bus + b * 2048 + wid * 512;
    gload16(hbf + prow0 * DH + k0 + schunk8, Ab);
    gload16(hbf + prow1 * DH + k0 + schunk8, Ab + 512);
    gload16(wgE + brow  * DH + k0 + schunk8, Gb);
    gload16(wuE + brow  * DH + k0 + schunk8, Ub);
  };

  auto compute = [&](int b) {
    const unsigned short* Ab = As  + b * 4096;
    const unsigned short* Gb = Bgs + b * 2048;
    const unsigned short* Ub = Bus + b * 2048;
    short8 a[4], bg[2], bu[2];
#pragma unroll
    for (int m = 0; m < 4; m++)
      a[m] = *(const short8*)(Ab + (wm * 64 + m * 16 + lr) * 32 + slot8);
#pragma unroll
    for (int n = 0; n < 2; n++) {
      bg[n] = *(const short8*)(Gb + (wn * 32 + n * 16 + lr) * 32 + slot8);
      bu[n] = *(const short8*)(Ub + (wn * 32 + n * 16 + lr) * 32 + slot8);
    }
#pragma unroll
    for (int m = 0; m < 4; m++)
#pragma unroll
      for (int n = 0; n < 2; n++) {
        accg[m][n] = __builtin_amdgcn_mfma_f32_16x16x32_bf16(a[m], bg[n], accg[m][n], 0, 0, 0);
        accu[m][n] = __builtin_amdgcn_mfma_f32_16x16x32_bf16(a[m], bu[n], accu[m][n], 0, 0, 0);
      }
  };

  // 3-stage pipeline over NT = 64 k-tiles; loads for tile i issued at i-2.
  const int NT = DH / 32;
  stage(0, 0);
  stage(1, 32);
  int bc = 0, bs = 2;
#pragma unroll 1
  for (int i = 0; i < NT - 1; ++i) {
    asm volatile("s_waitcnt vmcnt(4)" ::: "memory");   // oldest stage complete
    __builtin_amdgcn_s_barrier();
    __builtin_amdgcn_sched_barrier(0);
    compute(bc);
    if (i + 2 < NT) stage(bs, (i + 2) * 32);
    bc = (bc == 2) ? 0 : bc + 1;
    bs = (bs == 2) ? 0 : bs + 1;
  }
  asm volatile("s_waitcnt vmcnt(0)" ::: "memory");
  __builtin_amdgcn_s_barrier();
  __builtin_amdgcn_sched_barrier(0);
  compute(bc);

  // epilogue: silu(g)*u * w[t][e] -> bf16 hsC[e][row][i] (compacted rows)
#pragma unroll
  for (int m = 0; m < 4; m++) {
#pragma unroll
    for (int r = 0; r < 4; r++) {
      int mrow = m0 + wm * 64 + m * 16 + 4 * lgp + r;
      unsigned short en = L[mrow];
      if (en & 0x8000) continue;
      int tp = en & 0xFFF;
      float w = bf2f(dwb[(size_t)tp * 16 + e]);
#pragma unroll
      for (int n = 0; n < 2; n++) {
        float g = accg[m][n][r], u = accu[m][n][r];
        float sig = 1.f / (1.f + __expf(-g));
        float val = g * sig * u * w;
        hsC[((size_t)e * HSC_CAP + mrow) * DI + n0 + wn * 32 + n * 16 + lr] = f2bf(val);
      }
    }
  }
}

// ---- kernel 5: per-expert down GEMM (half of tokens) -> slot buffer -----
// A = hsC rows [rs+m0, ...) (contiguous compacted), B = dense wdbt rows with
// per-expert K-slice. Scatters 128x128 fp32 tile as bf16 into slot[s][tl][h].

__global__ __launch_bounds__(256, 3)
void down_half_k(const unsigned short* __restrict__ hsC,
                 const unsigned short* __restrict__ wdbt,
                 const unsigned short* __restrict__ lst,
                 const int* __restrict__ meta,
                 unsigned short* __restrict__ slotbuf, int hf) {
  // XCD-bijective swizzle: 2560 = 8 * 320; e-major -> n -> mtile
  const int bxr = blockIdx.x;
  const int wl  = (bxr & 7) * 320 + (bxr >> 3);
  const int e   = wl / 160;                 // 160 = 16 n-groups * 10 m-tiles
  const int rem = wl - e * 160;
  const int n0  = (rem / 10) * 128;
  const int m0  = (rem % 10) * 128;

  const int rs = hf ? meta[e * 2] : 0;
  const int re = hf ? meta[e * 2 + 1] : meta[e * 2];
  const int rcount = re - rs;
  if (m0 >= rcount) return;

  const int tid = threadIdx.x, lane = tid & 63, wid = tid >> 6;
  const int wm = wid >> 1, wn = wid & 1;
  const int lr = lane & 15, lgp = lane >> 4;

  __shared__ alignas(16) unsigned short As[3 * 128 * 32];  // 24KB
  __shared__ alignas(16) unsigned short Bs[3 * 128 * 32];  // 24KB

  f32x4 zero = {0.f, 0.f, 0.f, 0.f};
  f32x4 acc[4][4];
#pragma unroll
  for (int m = 0; m < 4; m++)
#pragma unroll
    for (int n = 0; n < 4; n++) acc[m][n] = zero;

  const int srow    = lane >> 2;
  const int schunk8 = (((lane & 3) - ((lane >> 3) & 3)) & 3) * 8;
  const int sOff0   = wid * 1024;
  const int sOff1   = sOff0 + 512;
  const size_t arow0 = (size_t)(e * HSC_CAP + rs + m0 + wid * 32 + srow);
  const size_t arow1 = arow0 + 16;
  const size_t brow0 = (size_t)(n0 + wid * 32 + srow), brow1 = brow0 + 16;
  const int slot8 = (((lane >> 4) + ((lane >> 1) & 3)) & 3) * 8;

  const unsigned short* wdE = wdbt + (size_t)e * DI;   // column block of dense rows

  auto stage = [&](int b, int k0) {           // 4 loads per wave
    unsigned short* Ab = As + b * 4096;
    unsigned short* Bb = Bs + b * 4096;
    gload16(hsC + arow0 * DI + k0 + schunk8, Ab + sOff0);
    gload16(hsC + arow1 * DI + k0 + schunk8, Ab + sOff1);
    gload16(wdE + brow0 * DKD + k0 + schunk8, Bb + sOff0);
    gload16(wdE + brow1 * DKD + k0 + schunk8, Bb + sOff1);
  };

  auto compute = [&](int bsel) {
    const unsigned short* Ab = As + bsel * 4096;
    const unsigned short* Bb = Bs + bsel * 4096;
    short8 a[4], b[4];
#pragma unroll
    for (int m = 0; m < 4; m++)
      a[m] = *(const short8*)(Ab + (size_t)(wm * 64 + m * 16 + lr) * 32 + slot8);
#pragma unroll
    for (int n = 0; n < 4; n++)
      b[n] = *(const short8*)(Bb + (size_t)(wn * 64 + n * 16 + lr) * 32 + slot8);
#pragma unroll
    for (int m = 0; m < 4; m++)
#pragma unroll
      for (int n = 0; n < 4; n++)
        acc[m][n] = __builtin_amdgcn_mfma_f32_16x16x32_bf16(a[m], b[n], acc[m][n], 0, 0, 0);
  };

  const int NT = DI / 32;                    // 24
  stage(0, 0);
  stage(1, 32);
  int bc = 0, bs = 2;
#pragma unroll 1
  for (int i = 0; i < NT - 1; ++i) {
    asm volatile("s_waitcnt vmcnt(4)" ::: "memory");
    __builtin_amdgcn_s_barrier();
    __builtin_amdgcn_sched_barrier(0);
    compute(bc);
    if (i + 2 < NT) stage(bs, (i + 2) * 32);
    bc = (bc == 2) ? 0 : bc + 1;
    bs = (bs == 2) ? 0 : bs + 1;
  }
  asm volatile("s_waitcnt vmcnt(0)" ::: "memory");
  __builtin_amdgcn_s_barrier();
  __builtin_amdgcn_sched_barrier(0);
  compute(bc);

  // epilogue: scatter rows into slot buffer (bf16)
  const unsigned short* L = lst + (size_t)e * NUM_T;
#pragma unroll
  for (int m = 0; m < 4; m++) {
#pragma unroll
    for (int r = 0; r < 4; r++) {
      int gr = m0 + wm * 64 + m * 16 + 4 * lgp + r;
      if (gr >= rcount) continue;
      unsigned short en = L[rs + gr];
      int t  = en & 0xFFF;
      int s  = (en >> 12) & 7;
      int tl = t - hf * TOK_HALF;
#pragma unroll
      for (int n = 0; n < 4; n++)
        slotbuf[((size_t)s * TOK_HALF + tl) * DH + n0 + wn * 64 + n * 16 + lr] =
            f2bf(acc[m][n][r]);
    }
  }
}

// ---- kernel 6: reduce 8 slots -> final fp32 output (one token half) -----

__global__ __launch_bounds__(256)
void reduce_half_k(const unsigned short* __restrict__ slotbuf,
                   float* __restrict__ outp, int hf) {
  size_t i  = (size_t)blockIdx.x * 256 + threadIdx.x;   // over 2048*256 chunks
  size_t tl = i >> 8;
  size_t h0 = (i & 255) * 8;
  float sum[8];
#pragma unroll
  for (int j = 0; j < 8; j++) sum[j] = 0.f;
#pragma unroll
  for (int s = 0; s < 8; s++) {
    short8 v = *(const short8*)(slotbuf + ((size_t)s * TOK_HALF + tl) * DH + h0);
#pragma unroll
    for (int j = 0; j < 8; j++) sum[j] += bf2f((unsigned short)v[j]);
  }
  float* o = outp + ((size_t)(hf * TOK_HALF) + tl) * DH + h0;
  float4 o0 = {sum[0], sum[1], sum[2], sum[3]};
  float4 o1 = {sum[4], sum[5], sum[6], sum[7]};
  *(float4*)o = o0;
  *(float4*)(o + 4) = o1;
}

// ---- launch --------------------------------------------------------------

extern "C" void kernel_launch(void* const* d_in, const int* in_sizes, int n_in,
                              void* d_out, int out_size, void* d_ws, size_t ws_size,
                              hipStream_t stream) {
  const float* x  = (const float*)d_in[0];   // [2,2048,2048]
  const float* wr = (const float*)d_in[1];   // [2048,16]
  const float* wg = (const float*)d_in[2];   // [16,2048,768]
  const float* wu = (const float*)d_in[3];   // [16,2048,768]
  const float* wd = (const float*)d_in[4];   // [16,768,2048]

  float* outF = (float*)d_out;               // final [T][H]
  float* outL = outF + FINAL_ELEMS;          // router logits [T][E]

  // workspace layout (bytes), total 180,682,880:
  //   hbf     @ 0          : 16,777,216   bf16 hidden [T][H]        (dead after gateup)
  //   wubt    @ 16,777,216 : 50,331,648   bf16 up B^T [E][I][H]     (dead after gateup)
  //   hsC     @ 67,108,864 : 62,914,560   bf16 compacted h [E][2560][I]
  //   wgbt    @ 130,023,424: 50,331,648   bf16 gate B^T [E][I][H]; reused as
  //                                       dense wdbt [H][E*I] after gateup
  //   dwb     @ 180,355,072: 131,072      bf16 combine weights [T][E]
  //   lst     @ 180,486,144: 131,072      u16 lists [E][T]: t | slot<<12
  //   slt     @ 180,617,216: 65,536       u8 slot table [T][E]
  //   meta    @ 180,682,752: 128          i32 {half0_count, total} per expert
  //   slotbuf @ 0 (aliases hbf+wubt): 67,108,864  bf16 [8][2048][H]
  if (ws_size < 180682880ull) return;
  char* ws = (char*)d_ws;
  unsigned short* hbf   = (unsigned short*)(ws);
  unsigned short* wubt  = (unsigned short*)(ws + 16777216);
  unsigned short* hsC   = (unsigned short*)(ws + 67108864);
  unsigned short* wgbt  = (unsigned short*)(ws + 130023424);
  unsigned short* dwb   = (unsigned short*)(ws + 180355072);
  unsigned short* lst   = (unsigned short*)(ws + 180486144);
  unsigned char*  slt   = (unsigned char*) (ws + 180617216);
  int*            meta  = (int*)           (ws + 180682752);
  unsigned short* sbuf  = (unsigned short*)(ws);            // aliases hbf+wubt
  unsigned short* wdbt  = wgbt;                             // reused after gateup

  cvt_hidden_k<<<4096, 256, 0, stream>>>(x, hbf);
  transpose_cvt_k<<<dim3(24, 64, 16), dim3(32, 8), 0, stream>>>(
      wg, wgbt, 2048, 768, (long)2048 * 768, (long)768 * 2048, 2048);
  transpose_cvt_k<<<dim3(24, 64, 16), dim3(32, 8), 0, stream>>>(
      wu, wubt, 2048, 768, (long)2048 * 768, (long)768 * 2048, 2048);
  router_k<<<4096, 256, 0, stream>>>(x, wr, outL, dwb, slt);
  build_lists_k<<<16, 256, 0, stream>>>(dwb, slt, lst, meta);
  gateup_k<<<3840, 256, 0, stream>>>(hbf, wgbt, wubt, dwb, lst, hsC);
  transpose_cvt_k<<<dim3(64, 24, 16), dim3(32, 8), 0, stream>>>(
      wd, wdbt, 768, 2048, (long)768 * 2048, 768L, 12288);
  down_half_k<<<2560, 256, 0, stream>>>(hsC, wdbt, lst, meta, sbuf, 0);
  reduce_half_k<<<2048, 256, 0, stream>>>(sbuf, outF, 0);
  down_half_k<<<2560, 256, 0, stream>>>(hsC, wdbt, lst, meta, sbuf, 1);
  reduce_half_k<<<2048, 256, 0, stream>>>(sbuf, outF, 1);
}